// Round 4
// baseline (158.643 us; speedup 1.0000x reference)
//
#include <hip/hip_runtime.h>

// LearnableTD reverse affine suffix scan, v3b.
// One block (256 thr) per row; each thread owns 8 contiguous timesteps.
// All global traffic is aligned 16B (misaligned rows handled via LDS
// staging + uniform shift-select). g and lambda[] precomputed once.

#define TPB 256
#define EPT 8          // elements per thread; tile = 2048 = T

typedef float v4f __attribute__((ext_vector_type(4)));   // native vec for NT stores

struct Aff { float aL, aS, b; };

__device__ inline Aff compose(const Aff& L, const Aff& R) {
    Aff o;
    o.aL = fmaf(L.b, R.aL, L.aL);
    o.aS = fmaf(L.b, R.aS, L.aS);
    o.b  = L.b * R.b;
    return o;
}

// lam[t] = 0.9 + 0.1*sigmoid(raw_lambd[start+t]);  lam[T] = gamma
__global__ void precompute_kernel(const float* __restrict__ raw_gamma,
                                  const float* __restrict__ raw_lambd,
                                  const int* __restrict__ start_p,
                                  float* __restrict__ lam, int T) {
    int t = blockIdx.x * blockDim.x + threadIdx.x;
    if (t < T) lam[t] = 0.9f + 0.1f / (1.0f + __expf(-raw_lambd[start_p[0] + t]));
    if (t == 0) lam[T] = 0.98f + 0.02f / (1.0f + __expf(-raw_gamma[0]));
}

__global__ __launch_bounds__(TPB, 8)
void td_scan_kernel(const float* __restrict__ values,    // B x (T+1)
                    const float* __restrict__ rewards,   // B x T
                    const float* __restrict__ dones,     // B x T
                    const float* __restrict__ lam_arr,   // T lambdas + [T]=g
                    float* __restrict__ out,             // B*(T+1) lam ++ B*T sum
                    int B, int T)
{
    __shared__ __align__(16) float s_buf[2064];
    __shared__ float s_wAL[4], s_wAS[4], s_wB[4], s_cL[4], s_cS[4];

    const int b    = blockIdx.x;
    const int tid  = threadIdx.x;
    const int lane = tid & 63;
    const int wave = tid >> 6;
    const int nwaves = TPB >> 6;          // 4

    const float g = lam_arr[T];           // uniform scalar load

    const size_t rowV = (size_t)b * (T + 1);
    const float* rrow = rewards + (size_t)b * T;
    const float* drow = dones   + (size_t)b * T;

    // ---- stage values[rowV+1 .. rowV+T] into s_buf (aligned f4 loads) ----
    const size_t firstNeeded = rowV + 1;
    const int off = (int)(firstNeeded & 3);       // uniform per block
    const size_t A = firstNeeded - off;           // 16B-aligned global elem idx
    const int nStage = T + off;                   // covers s_buf[off .. off+T-1]
    const int n4 = (nStage + 3) >> 2;
    const size_t totalElems = (size_t)B * (T + 1);
    for (int j = tid; j < n4; j += TPB) {
        const size_t gb = A + 4 * (size_t)j;
        if (gb + 3 < totalElems) {
            *(v4f*)(s_buf + 4 * j) = *(const v4f*)(values + gb);
        } else {
            #pragma unroll
            for (int c = 0; c < 4; ++c)
                s_buf[4 * j + c] = (gb + c < totalElems) ? values[gb + c] : 0.0f;
        }
    }
    __syncthreads();

    const float vT = s_buf[off + T - 1];          // values[:, T] (broadcast read)

    // ---- per-thread loads (all aligned float4) ----
    const int base = tid * EPT;
    float r[EPT], d[EPT], l[EPT], vn[EPT];
    {
        const v4f r0 = *(const v4f*)(rrow + base);
        const v4f r1 = *(const v4f*)(rrow + base + 4);
        const v4f d0 = *(const v4f*)(drow + base);
        const v4f d1 = *(const v4f*)(drow + base + 4);
        const v4f l0 = *(const v4f*)(lam_arr + base);
        const v4f l1 = *(const v4f*)(lam_arr + base + 4);
        r[0]=r0.x; r[1]=r0.y; r[2]=r0.z; r[3]=r0.w; r[4]=r1.x; r[5]=r1.y; r[6]=r1.z; r[7]=r1.w;
        d[0]=d0.x; d[1]=d0.y; d[2]=d0.z; d[3]=d0.w; d[4]=d1.x; d[5]=d1.y; d[6]=d1.z; d[7]=d1.w;
        l[0]=l0.x; l[1]=l0.y; l[2]=l0.z; l[3]=l0.w; l[4]=l1.x; l[5]=l1.y; l[6]=l1.z; l[7]=l1.w;
    }
    {   // vn[k] = values[rowV + base + k + 1] = s_buf[off + base + k]
        const v4f w0 = *(const v4f*)(s_buf + base);       // 32B-aligned
        const v4f w1 = *(const v4f*)(s_buf + base + 4);
        const v4f w2 = *(const v4f*)(s_buf + base + 8);
        switch (off) {   // uniform branch
        case 0: vn[0]=w0.x; vn[1]=w0.y; vn[2]=w0.z; vn[3]=w0.w; vn[4]=w1.x; vn[5]=w1.y; vn[6]=w1.z; vn[7]=w1.w; break;
        case 1: vn[0]=w0.y; vn[1]=w0.z; vn[2]=w0.w; vn[3]=w1.x; vn[4]=w1.y; vn[5]=w1.z; vn[6]=w1.w; vn[7]=w2.x; break;
        case 2: vn[0]=w0.z; vn[1]=w0.w; vn[2]=w1.x; vn[3]=w1.y; vn[4]=w1.z; vn[5]=w1.w; vn[6]=w2.x; vn[7]=w2.y; break;
        default: vn[0]=w0.w; vn[1]=w1.x; vn[2]=w1.y; vn[3]=w1.z; vn[4]=w1.w; vn[5]=w2.x; vn[6]=w2.y; vn[7]=w2.z; break;
        }
    }

    // ---- per-thread affine maps + serial composite ----
    Aff M[EPT];
    #pragma unroll
    for (int k = 0; k < EPT; ++k) {
        const float cont = g * (1.0f - d[k]);
        M[k].b  = cont * l[k];
        M[k].aL = fmaf(cont * (1.0f - l[k]), vn[k], r[k]);
        M[k].aS = r[k];
    }
    Aff C = M[EPT - 1];
    #pragma unroll
    for (int k = EPT - 2; k >= 0; --k) C = compose(M[k], C);

    // ---- wave-level inclusive suffix scan ----
    Aff S = C;
    #pragma unroll
    for (int dlt = 1; dlt < 64; dlt <<= 1) {
        Aff oth;
        oth.aL = __shfl_down(S.aL, dlt, 64);
        oth.aS = __shfl_down(S.aS, dlt, 64);
        oth.b  = __shfl_down(S.b,  dlt, 64);
        if (lane + dlt < 64) S = compose(S, oth);
    }
    // exclusive suffix within wave
    Aff E;
    E.aL = __shfl_down(S.aL, 1, 64);
    E.aS = __shfl_down(S.aS, 1, 64);
    E.b  = __shfl_down(S.b,  1, 64);
    if (lane == 63) { E.aL = 0.0f; E.aS = 0.0f; E.b = 1.0f; }

    if (lane == 0) { s_wAL[wave] = S.aL; s_wAS[wave] = S.aS; s_wB[wave] = S.b; }
    __syncthreads();

    if (tid == 0) {
        float cL = vT, cS = 0.0f;
        for (int w = nwaves - 1; w >= 0; --w) {
            s_cL[w] = cL; s_cS[w] = cS;
            const float wb = s_wB[w];
            cL = fmaf(wb, cL, s_wAL[w]);
            cS = fmaf(wb, cS, s_wAS[w]);
        }
    }
    __syncthreads();

    // ---- apply carry right-to-left through the 8 owned elements ----
    const float cwL = s_cL[wave];
    const float cwS = s_cS[wave];
    float xL = fmaf(E.b, cwL, E.aL);
    float xS = fmaf(E.b, cwS, E.aS);
    float oL[EPT], oS[EPT];
    #pragma unroll
    for (int k = EPT - 1; k >= 0; --k) {
        xL = fmaf(M[k].b, xL, M[k].aL);
        xS = fmaf(M[k].b, xS, M[k].aS);
        oL[k] = xL; oS[k] = xS;
    }

    // ---- sum_rewards: rows always 16B-aligned, direct f4 NT stores ----
    float* sum_out = out + (size_t)B * (T + 1) + (size_t)b * T;
    {
        v4f s0 = { oS[0], oS[1], oS[2], oS[3] };
        v4f s1 = { oS[4], oS[5], oS[6], oS[7] };
        __builtin_nontemporal_store(s0, (v4f*)(sum_out + base));
        __builtin_nontemporal_store(s1, (v4f*)(sum_out + base + 4));
    }

    // ---- lambda_returns: stage row in LDS, store with aligned f4s ----
    #pragma unroll
    for (int k = 0; k < EPT; ++k) s_buf[base + k] = oL[k];
    if (tid == 0) s_buf[T] = vT;
    __syncthreads();

    const size_t O = (size_t)b * (T + 1);          // elem offset of lam row
    const int sh = (int)((4 - (O & 3)) & 3);       // first aligned elem = O+sh
    if (tid < sh) out[O + tid] = s_buf[tid];       // head (<=3 scalars)
    const int rem  = T + 1 - sh;
    const int m4   = rem >> 2;
    const int tail = rem & 3;
    for (int j = tid; j < m4; j += TPB) {
        const int ls = sh + 4 * j;                 // local start; ls % 4 == sh
        const v4f lo = *(const v4f*)(s_buf + (ls - sh));
        const v4f hi = *(const v4f*)(s_buf + (ls - sh) + 4);
        v4f v;
        switch (sh) {   // uniform branch
        case 0:  v = lo; break;
        case 1:  v = (v4f){ lo.y, lo.z, lo.w, hi.x }; break;
        case 2:  v = (v4f){ lo.z, lo.w, hi.x, hi.y }; break;
        default: v = (v4f){ lo.w, hi.x, hi.y, hi.z }; break;
        }
        __builtin_nontemporal_store(v, (v4f*)(out + O + ls));
    }
    if (tid < tail) { const int ls = sh + 4 * m4 + tid; out[O + ls] = s_buf[ls]; }
}

extern "C" void kernel_launch(void* const* d_in, const int* in_sizes, int n_in,
                              void* d_out, int out_size, void* d_ws, size_t ws_size,
                              hipStream_t stream) {
    const float* values    = (const float*)d_in[0];
    const float* rewards   = (const float*)d_in[1];
    const float* dones     = (const float*)d_in[2];
    const float* raw_gamma = (const float*)d_in[3];
    const float* raw_lambd = (const float*)d_in[4];
    const int*   start_idx = (const int*)d_in[5];
    float* out = (float*)d_out;
    float* lam_arr = (float*)d_ws;        // T lambdas + 1 gamma

    const int n_values  = in_sizes[0];    // B*(T+1)
    const int n_rewards = in_sizes[1];    // B*T
    const int B = n_values - n_rewards;
    const int T = n_rewards / B;

    precompute_kernel<<<(T + 256) / 256, 256, 0, stream>>>(raw_gamma, raw_lambd,
                                                           start_idx, lam_arr, T);
    td_scan_kernel<<<B, TPB, 0, stream>>>(values, rewards, dones, lam_arr, out, B, T);
}